// Round 1
// baseline (733.696 us; speedup 1.0000x reference)
//
#include <hip/hip_runtime.h>
#include <math.h>

#define N_NODES 50000
#define DEG 32
#define WIDTH 128
#define BATCH 4096
#define EPS 1e-12f

typedef float4 f4;

// ---------------- small helper kernels ----------------

__global__ void init_inv_k(int* __restrict__ inv) {
    int i = blockIdx.x * blockDim.x + threadIdx.x;
    if (i < N_NODES) inv[i] = -1;
}

__global__ void scatter_inv_k(const int* __restrict__ node_idx, int* __restrict__ inv) {
    int i = blockIdx.x * blockDim.x + threadIdx.x;
    if (i < BATCH) atomicMax(&inv[node_idx[i]], i);  // last-write-wins == max batch index
}

// WT[k*ocount + o] = W[o*kcount + k]
__global__ void transpose_k(const float* __restrict__ W, float* __restrict__ WT,
                            int ocount, int kcount) {
    int idx = blockIdx.x * blockDim.x + threadIdx.x;
    if (idx < ocount * kcount) {
        int o = idx / kcount, k = idx - o * kcount;
        WT[k * ocount + o] = W[idx];
    }
}

// AGG1[n] = max over neighbors nb of M0[nb], where M0[nb] = relu(b_agg) for cold
// nodes and M0b[inv[nb]] for batch nodes. One block (128 thr) per node.
__global__ void agg1_k(const int* __restrict__ nbd, const int* __restrict__ inv,
                       const float* __restrict__ M0b, const float* __restrict__ b_agg,
                       float* __restrict__ AGG1) {
    int n = blockIdx.x;
    int t = threadIdx.x;
    __shared__ int nb[DEG];
    if (t < DEG) nb[t] = inv[nbd[n * DEG + t]];
    __syncthreads();
    bool anyCold = false;
#pragma unroll
    for (int j = 0; j < DEG; ++j) anyCold |= (nb[j] < 0);
    float acc = -3.402823466e+38f;
    if (anyCold) {
        float b = b_agg[t];
        acc = b > 0.f ? b : 0.f;   // relu(b_agg)
    }
    for (int j = 0; j < DEG; ++j) {
        int bi = nb[j];
        if (bi >= 0) acc = fmaxf(acc, M0b[(size_t)bi * WIDTH + t]);
    }
    AGG1[(size_t)n * WIDTH + t] = acc;
}

// AGG2[i] = max over neighbors of node_idx[i] of M1[nb]. Block per batch row.
__global__ void agg2_k(const int* __restrict__ nbd, const int* __restrict__ node_idx,
                       const float* __restrict__ M1, float* __restrict__ AGG2) {
    int i = blockIdx.x;
    int t = threadIdx.x;
    __shared__ int nb[DEG];
    int n = node_idx[i];
    if (t < DEG) nb[t] = nbd[n * DEG + t];
    __syncthreads();
    float acc = -3.402823466e+38f;
#pragma unroll
    for (int j = 0; j < DEG; ++j) acc = fmaxf(acc, M1[(size_t)nb[j] * WIDTH + t]);
    AGG2[(size_t)i * WIDTH + t] = acc;
}

// HB1[i] = H1[node_idx[i]]
__global__ void gatherH1_k(const int* __restrict__ node_idx, const float* __restrict__ H1,
                           float* __restrict__ HB1) {
    int i = blockIdx.x;
    int t = threadIdx.x;
    HB1[(size_t)i * WIDTH + t] = H1[(size_t)node_idx[i] * WIDTH + t];
}

// ---------------- register-tiled f32 GEMM ----------------
// out[m][o] = epilogue( sum_k A[m][k] * WT[k][o] + bias[o] (+ addin[m][o]) (+ S[inv[m]][o]) )
// K fixed at 128, N fixed at 128. 64-row tiles, 256 threads, 8 rows x 4 cols per thread.
#define TM 64

template <bool RELU, bool NORM, bool HAS_BIAS, bool HAS_ADDIN, bool HAS_S>
__global__ __launch_bounds__(256, 2) void gemm_k(
    const float* __restrict__ A, const float* __restrict__ WT,
    const float* __restrict__ bias, const float* __restrict__ addin,
    const float* __restrict__ S, const int* __restrict__ inv,
    float* __restrict__ out, int M) {
    __shared__ __align__(16) float As[TM * 128];
    __shared__ __align__(16) float Ws[64 * 128];

    int tid = threadIdx.x;
    int row0 = blockIdx.x * TM;
    int cg = tid & 31;   // col group: cols 4*cg .. 4*cg+3
    int rg = tid >> 5;   // row group: rows rg*8 .. rg*8+7

    // stage A tile [64][128] (zero-fill past M)
    {
        int r = tid >> 5;
        int k4 = tid & 31;
        for (int s = 0; s < 8; ++s) {
            int rr = s * 8 + r;
            int grow = row0 + rr;
            f4 v = make_float4(0.f, 0.f, 0.f, 0.f);
            if (grow < M) v = *(const f4*)(A + (size_t)grow * 128 + k4 * 4);
            *(f4*)(As + rr * 128 + k4 * 4) = v;
        }
    }

    float acc[8][4];
#pragma unroll
    for (int i = 0; i < 8; ++i)
#pragma unroll
        for (int j = 0; j < 4; ++j) acc[i][j] = 0.f;

    for (int kc = 0; kc < 2; ++kc) {
        __syncthreads();  // A visible (kc=0) / previous chunk compute done (kc=1)
        // stage Ws[kk][c] = WT[(kc*64+kk)*128 + c], vectorized
        for (int s = 0; s < 8; ++s) {
            int idx4 = tid + s * 256;          // 2048 float4 total
            int kk = idx4 >> 5, c4 = idx4 & 31;
            *(f4*)(Ws + kk * 128 + c4 * 4) =
                *(const f4*)(WT + (size_t)(kc * 64 + kk) * 128 + c4 * 4);
        }
        __syncthreads();
#pragma unroll
        for (int k4 = 0; k4 < 16; ++k4) {
            f4 w0 = *(f4*)(Ws + (k4 * 4 + 0) * 128 + cg * 4);
            f4 w1 = *(f4*)(Ws + (k4 * 4 + 1) * 128 + cg * 4);
            f4 w2 = *(f4*)(Ws + (k4 * 4 + 2) * 128 + cg * 4);
            f4 w3 = *(f4*)(Ws + (k4 * 4 + 3) * 128 + cg * 4);
#pragma unroll
            for (int i = 0; i < 8; ++i) {
                f4 a = *(f4*)(As + (rg * 8 + i) * 128 + kc * 64 + k4 * 4);
                acc[i][0] += a.x * w0.x + a.y * w1.x + a.z * w2.x + a.w * w3.x;
                acc[i][1] += a.x * w0.y + a.y * w1.y + a.z * w2.y + a.w * w3.y;
                acc[i][2] += a.x * w0.z + a.y * w1.z + a.z * w2.z + a.w * w3.z;
                acc[i][3] += a.x * w0.w + a.y * w1.w + a.z * w2.w + a.w * w3.w;
            }
        }
    }

    // epilogue
    int c0 = cg * 4;
    float b0 = 0.f, b1 = 0.f, b2 = 0.f, b3 = 0.f;
    if (HAS_BIAS) {
        f4 b = *(const f4*)(bias + c0);
        b0 = b.x; b1 = b.y; b2 = b.z; b3 = b.w;
    }
#pragma unroll
    for (int i = 0; i < 8; ++i) {
        int rr = rg * 8 + i;
        int grow = row0 + rr;
        if (grow >= M) continue;  // uniform across the 32-lane col group
        float v[4];
        v[0] = acc[i][0] + b0; v[1] = acc[i][1] + b1;
        v[2] = acc[i][2] + b2; v[3] = acc[i][3] + b3;
        if (HAS_ADDIN) {
            f4 ad = *(const f4*)(addin + (size_t)grow * 128 + c0);
            v[0] += ad.x; v[1] += ad.y; v[2] += ad.z; v[3] += ad.w;
        }
        if (HAS_S) {
            int bi = inv[grow];
            if (bi >= 0) {
                f4 sv = *(const f4*)(S + (size_t)bi * 128 + c0);
                v[0] += sv.x; v[1] += sv.y; v[2] += sv.z; v[3] += sv.w;
            }
        }
        if (RELU) {
#pragma unroll
            for (int j = 0; j < 4; ++j) v[j] = fmaxf(v[j], 0.f);
        }
        if (NORM) {
            float p = v[0] * v[0] + v[1] * v[1] + v[2] * v[2] + v[3] * v[3];
            p += __shfl_xor(p, 1);
            p += __shfl_xor(p, 2);
            p += __shfl_xor(p, 4);
            p += __shfl_xor(p, 8);
            p += __shfl_xor(p, 16);
            float s = 1.0f / fmaxf(sqrtf(p), EPS);
#pragma unroll
            for (int j = 0; j < 4; ++j) v[j] *= s;
        }
        *(f4*)(out + (size_t)grow * 128 + c0) = make_float4(v[0], v[1], v[2], v[3]);
    }
}

// ---------------- launch ----------------

extern "C" void kernel_launch(void* const* d_in, const int* in_sizes, int n_in,
                              void* d_out, int out_size, void* d_ws, size_t ws_size,
                              hipStream_t stream) {
    const int*   nbd      = (const int*)d_in[0];
    const int*   node_idx = (const int*)d_in[1];
    const float* feats    = (const float*)d_in[2];
    const float* W_agg    = (const float*)d_in[3];
    const float* b_agg    = (const float*)d_in[4];
    const float* W_lin    = (const float*)d_in[5];
    const float* b_lin    = (const float*)d_in[6];
    float* out = (float*)d_out;

    // workspace layout (floats)
    float* ws    = (float*)d_ws;
    int*   inv   = (int*)d_ws;            // 50000 ints (pad to 50048)
    float* WaggT = ws + 50048;            // 16384
    float* WlinT = WaggT + 16384;         // 32768 (rows 0..127 = Wself^T, 128..255 = Wagg-part^T)
    float* M0b   = WlinT + 32768;         // 4096*128
    float* S     = M0b + BATCH * WIDTH;   // 4096*128
    float* AGG1  = S + BATCH * WIDTH;     // 50000*128  (reused as M1 later)
    float* H1    = AGG1 + (size_t)N_NODES * WIDTH;  // 50000*128
    float* AGG2  = H1 + (size_t)N_NODES * WIDTH;    // 4096*128
    float* HB1   = AGG2 + BATCH * WIDTH;  // 4096*128
    float* T2    = HB1 + BATCH * WIDTH;   // 4096*128
    float* M1    = AGG1;                  // alias: AGG1 dead after H1 GEMM

    const int GB = (N_NODES + TM - 1) / TM;  // 782
    const int BB = BATCH / TM;               // 64

    // owner map (last-write-wins scatter semantics)
    init_inv_k<<<(N_NODES + 255) / 256, 256, 0, stream>>>(inv);
    scatter_inv_k<<<(BATCH + 255) / 256, 256, 0, stream>>>(node_idx, inv);

    // transposed weights
    transpose_k<<<(128 * 128 + 255) / 256, 256, 0, stream>>>(W_agg, WaggT, 128, 128);
    transpose_k<<<(128 * 256 + 255) / 256, 256, 0, stream>>>(W_lin, WlinT, 128, 256);

    // M0b = relu(feats @ W_agg.T + b_agg)   [4096,128]
    gemm_k<true, false, true, false, false><<<BB, 256, 0, stream>>>(
        feats, WaggT, b_agg, nullptr, nullptr, nullptr, M0b, BATCH);

    // S = feats @ Wself.T (no bias/relu)    [4096,128]
    gemm_k<false, false, false, false, false><<<BB, 256, 0, stream>>>(
        feats, WlinT, nullptr, nullptr, nullptr, nullptr, S, BATCH);

    // AGG1 via cold-node shortcut           [50000,128]
    agg1_k<<<N_NODES, WIDTH, 0, stream>>>(nbd, inv, M0b, b_agg, AGG1);

    // H1 = normalize(relu(AGG1 @ Wap.T + S[inv] + b_lin))  [50000,128]
    gemm_k<true, true, true, false, true><<<GB, 256, 0, stream>>>(
        AGG1, WlinT + 128 * 128, b_lin, nullptr, S, inv, H1, N_NODES);

    // M1 = relu(H1 @ W_agg.T + b_agg)       [50000,128]  (writes over AGG1)
    gemm_k<true, false, true, false, false><<<GB, 256, 0, stream>>>(
        H1, WaggT, b_agg, nullptr, nullptr, nullptr, M1, N_NODES);

    // batch-row gathers for hop 2
    gatherH1_k<<<BATCH, WIDTH, 0, stream>>>(node_idx, H1, HB1);
    agg2_k<<<BATCH, WIDTH, 0, stream>>>(nbd, node_idx, M1, AGG2);

    // T2 = HB1 @ Wself.T
    gemm_k<false, false, false, false, false><<<BB, 256, 0, stream>>>(
        HB1, WlinT, nullptr, nullptr, nullptr, nullptr, T2, BATCH);

    // out = normalize(relu(AGG2 @ Wap.T + T2 + b_lin))   [4096,128]
    gemm_k<true, true, true, true, false><<<BB, 256, 0, stream>>>(
        AGG2, WlinT + 128 * 128, b_lin, T2, nullptr, nullptr, out, BATCH);
}

// Round 2
// 127.793 us; speedup vs baseline: 5.7413x; 5.7413x over previous
//
#include <hip/hip_runtime.h>
#include <math.h>

#define N_NODES 50000
#define DEG 32
#define WIDTH 128
#define BATCH 4096
#define EPS 1e-12f

typedef __attribute__((ext_vector_type(8))) short short8;   // 8 bf16 (4 VGPRs)
typedef __attribute__((ext_vector_type(4))) float f32x4;    // MFMA accumulator

typedef unsigned short ushort_t;

__device__ __forceinline__ float bf2f(ushort_t u) {
    unsigned v = ((unsigned)u) << 16;
    float f;
    __builtin_memcpy(&f, &v, 4);
    return f;
}
__device__ __forceinline__ ushort_t f2bf(float f) {
    unsigned x;
    __builtin_memcpy(&x, &f, 4);
    unsigned r = (x + 0x7fff + ((x >> 16) & 1)) >> 16;  // RNE
    return (ushort_t)r;
}

// ---------------- small helper kernels ----------------

__global__ void init_inv_k(int* __restrict__ inv) {
    int i = blockIdx.x * blockDim.x + threadIdx.x;
    if (i < N_NODES) inv[i] = -1;
}

__global__ void scatter_inv_k(const int* __restrict__ node_idx, int* __restrict__ inv) {
    int i = blockIdx.x * blockDim.x + threadIdx.x;
    if (i < BATCH) atomicMax(&inv[node_idx[i]], i);  // last-write-wins == max batch index
}

__global__ void cvt_k(const float* __restrict__ a, ushort_t* __restrict__ b, int n) {
    int i = blockIdx.x * blockDim.x + threadIdx.x;
    if (i < n) b[i] = f2bf(a[i]);
}

// AGG1[n] = max over neighbors nb of M0[nb]; M0[nb] = relu(b_agg) for cold nodes,
// M0b[inv[nb]] for batch nodes. One block (128 thr) per node. bf16 output.
__global__ void agg1_k(const int* __restrict__ nbd, const int* __restrict__ inv,
                       const float* __restrict__ M0b, const float* __restrict__ b_agg,
                       ushort_t* __restrict__ AGG1) {
    int n = blockIdx.x;
    int t = threadIdx.x;
    __shared__ int nb[DEG];
    if (t < DEG) nb[t] = inv[nbd[n * DEG + t]];
    __syncthreads();
    bool anyCold = false;
#pragma unroll
    for (int j = 0; j < DEG; ++j) anyCold |= (nb[j] < 0);
    float acc = -3.402823466e+38f;
    if (anyCold) acc = fmaxf(b_agg[t], 0.f);  // relu(b_agg)
    for (int j = 0; j < DEG; ++j) {
        int bi = nb[j];
        if (bi >= 0) acc = fmaxf(acc, M0b[(size_t)bi * WIDTH + t]);
    }
    AGG1[(size_t)n * WIDTH + t] = f2bf(acc);
}

// AGG2[i] = max over neighbors of node_idx[i] of M1[nb] (bf16 in, bf16 out).
__global__ void agg2_k(const int* __restrict__ nbd, const int* __restrict__ node_idx,
                       const ushort_t* __restrict__ M1, ushort_t* __restrict__ AGG2) {
    int i = blockIdx.x;
    int t = threadIdx.x;
    __shared__ int nb[DEG];
    int n = node_idx[i];
    if (t < DEG) nb[t] = nbd[n * DEG + t];
    __syncthreads();
    float acc = -3.402823466e+38f;
#pragma unroll
    for (int j = 0; j < DEG; ++j) acc = fmaxf(acc, bf2f(M1[(size_t)nb[j] * WIDTH + t]));
    AGG2[(size_t)i * WIDTH + t] = f2bf(acc);
}

// HB1[i] = H1[node_idx[i]] (bf16)
__global__ void gatherH1_k(const int* __restrict__ node_idx, const ushort_t* __restrict__ H1,
                           ushort_t* __restrict__ HB1) {
    int i = blockIdx.x;
    int t = threadIdx.x;
    HB1[(size_t)i * WIDTH + t] = H1[(size_t)node_idx[i] * WIDTH + t];
}

// ---------------- MFMA bf16 GEMM ----------------
// out[m][o] = epi( sum_{k<128} A[m][k]*W[o][k] + bias[o] (+addin[m][o]) (+S[inv[m]][o]) )
// A: [M][128] bf16 row-major. W: row o at W + o*ldw (bf16), 128 k-elems used.
// Block = 256 thr = 4 waves; tile 64 rows x 128 cols; wave w owns rows w*16..w*16+15.
// mfma_f32_16x16x32_bf16: A-frag lane l: row=l&15, k=(l>>4)*8+j (8 contiguous);
// B-frag lane l: col=l&15, k=(l>>4)*8+j  => lane reads W[col][k..k+8) contiguously.
// D: col=lane&15, row=(lane>>4)*4+reg   (m89-verified).

template <bool RELU, bool NORM, bool HAS_BIAS, bool HAS_ADDIN, bool HAS_S, bool OUT_BF16>
__global__ __launch_bounds__(256) void mgemm(
    const ushort_t* __restrict__ A,
    const ushort_t* __restrict__ W, int ldw,
    const float* __restrict__ bias, const float* __restrict__ addin,
    const float* __restrict__ S, const int* __restrict__ inv,
    void* __restrict__ outv, int M) {
    int tid = threadIdx.x;
    int w = tid >> 6;
    int l = tid & 63;
    int li = l & 15;       // row (A) / col (B,D) within fragment
    int kq = l >> 4;       // k-quad: k = kq*8 + j within each 32-chunk
    int row0 = blockIdx.x * 64 + w * 16;

    int arow = row0 + li;
    if (arow > M - 1) arow = M - 1;  // clamp (stores guarded below)

    f32x4 acc[8];
#pragma unroll
    for (int n = 0; n < 8; ++n) acc[n] = (f32x4){0.f, 0.f, 0.f, 0.f};

#pragma unroll
    for (int kk = 0; kk < 4; ++kk) {
        short8 a = *(const short8*)(A + (size_t)arow * 128 + kk * 32 + kq * 8);
#pragma unroll
        for (int n = 0; n < 8; ++n) {
            short8 b = *(const short8*)(W + (size_t)(n * 16 + li) * ldw + kk * 32 + kq * 8);
            acc[n] = __builtin_amdgcn_mfma_f32_16x16x32_bf16(a, b, acc[n], 0, 0, 0);
        }
    }

    float bv[8];
#pragma unroll
    for (int n = 0; n < 8; ++n) bv[n] = HAS_BIAS ? bias[n * 16 + li] : 0.f;

    float* outf = (float*)outv;
    ushort_t* outb = (ushort_t*)outv;

#pragma unroll
    for (int r = 0; r < 4; ++r) {
        int row = kq * 4 + r;
        int grow = row0 + row;
        int growc = grow < M ? grow : M - 1;
        float v[8];
#pragma unroll
        for (int n = 0; n < 8; ++n) v[n] = acc[n][r] + bv[n];
        if (HAS_ADDIN) {
#pragma unroll
            for (int n = 0; n < 8; ++n) v[n] += addin[(size_t)growc * 128 + n * 16 + li];
        }
        if (HAS_S) {
            int bi = inv[growc];
            if (bi >= 0) {
#pragma unroll
                for (int n = 0; n < 8; ++n) v[n] += S[(size_t)bi * 128 + n * 16 + li];
            }
        }
        if (RELU) {
#pragma unroll
            for (int n = 0; n < 8; ++n) v[n] = fmaxf(v[n], 0.f);
        }
        if (NORM) {
            float p = 0.f;
#pragma unroll
            for (int n = 0; n < 8; ++n) p += v[n] * v[n];
            // 16 lanes (same kq, same r) share this output row
            p += __shfl_xor(p, 1);
            p += __shfl_xor(p, 2);
            p += __shfl_xor(p, 4);
            p += __shfl_xor(p, 8);
            float s = 1.0f / fmaxf(sqrtf(p), EPS);
#pragma unroll
            for (int n = 0; n < 8; ++n) v[n] *= s;
        }
        if (grow < M) {
#pragma unroll
            for (int n = 0; n < 8; ++n) {
                if (OUT_BF16)
                    outb[(size_t)grow * 128 + n * 16 + li] = f2bf(v[n]);
                else
                    outf[(size_t)grow * 128 + n * 16 + li] = v[n];
            }
        }
    }
}

// ---------------- launch ----------------

extern "C" void kernel_launch(void* const* d_in, const int* in_sizes, int n_in,
                              void* d_out, int out_size, void* d_ws, size_t ws_size,
                              hipStream_t stream) {
    const int*   nbd      = (const int*)d_in[0];
    const int*   node_idx = (const int*)d_in[1];
    const float* feats    = (const float*)d_in[2];
    const float* W_agg    = (const float*)d_in[3];
    const float* b_agg    = (const float*)d_in[4];
    const float* W_lin    = (const float*)d_in[5];
    const float* b_lin    = (const float*)d_in[6];
    float* out = (float*)d_out;

    // workspace layout (byte offsets, all 16B-aligned)
    char* base = (char*)d_ws;
    size_t off = 0;
    int*      inv    = (int*)(base + off);      off += 50048 * 4;           // 200192
    ushort_t* Wab    = (ushort_t*)(base + off); off += 16384 * 2;           // bf16 W_agg [128][128]
    ushort_t* Wlb    = (ushort_t*)(base + off); off += 32768 * 2;           // bf16 W_lin [128][256]
    ushort_t* featsb = (ushort_t*)(base + off); off += (size_t)BATCH * 128 * 2;
    float*    M0b    = (float*)(base + off);    off += (size_t)BATCH * 128 * 4;
    float*    S      = (float*)(base + off);    off += (size_t)BATCH * 128 * 4;
    ushort_t* AGG1b  = (ushort_t*)(base + off); off += (size_t)N_NODES * 128 * 2;
    ushort_t* H1b    = (ushort_t*)(base + off); off += (size_t)N_NODES * 128 * 2;
    ushort_t* HB1b   = (ushort_t*)(base + off); off += (size_t)BATCH * 128 * 2;
    ushort_t* AGG2b  = (ushort_t*)(base + off); off += (size_t)BATCH * 128 * 2;
    float*    T2     = (float*)(base + off);    off += (size_t)BATCH * 128 * 4;
    ushort_t* M1b    = AGG1b;  // alias: AGG1 dead after the H1 GEMM

    const int GB = (N_NODES + 63) / 64;  // 782
    const int BB = BATCH / 64;           // 64

    // owner map (last-write-wins scatter semantics)
    init_inv_k<<<(N_NODES + 255) / 256, 256, 0, stream>>>(inv);
    scatter_inv_k<<<(BATCH + 255) / 256, 256, 0, stream>>>(node_idx, inv);

    // bf16 conversions
    cvt_k<<<(16384 + 255) / 256, 256, 0, stream>>>(W_agg, Wab, 16384);
    cvt_k<<<(32768 + 255) / 256, 256, 0, stream>>>(W_lin, Wlb, 32768);
    cvt_k<<<(BATCH * 128 + 255) / 256, 256, 0, stream>>>(feats, featsb, BATCH * 128);

    // M0b = relu(feats @ W_agg.T + b_agg)  [4096,128] f32
    mgemm<true, false, true, false, false, false><<<BB, 256, 0, stream>>>(
        featsb, Wab, 128, b_agg, nullptr, nullptr, nullptr, M0b, BATCH);

    // S = feats @ Wself.T  (W_lin[:, :128])  [4096,128] f32
    mgemm<false, false, false, false, false, false><<<BB, 256, 0, stream>>>(
        featsb, Wlb, 256, nullptr, nullptr, nullptr, nullptr, S, BATCH);

    // AGG1 via cold-node shortcut  [50000,128] bf16
    agg1_k<<<N_NODES, WIDTH, 0, stream>>>(nbd, inv, M0b, b_agg, AGG1b);

    // H1 = normalize(relu(AGG1 @ Wagg-part.T + S[inv] + b_lin))  [50000,128] bf16
    mgemm<true, true, true, false, true, true><<<GB, 256, 0, stream>>>(
        AGG1b, Wlb + 128, 256, b_lin, nullptr, S, inv, H1b, N_NODES);

    // M1 = relu(H1 @ W_agg.T + b_agg)  [50000,128] bf16 (overwrites AGG1)
    mgemm<true, false, true, false, false, true><<<GB, 256, 0, stream>>>(
        H1b, Wab, 128, b_agg, nullptr, nullptr, nullptr, M1b, N_NODES);

    // batch-row gathers for hop 2
    gatherH1_k<<<BATCH, WIDTH, 0, stream>>>(node_idx, H1b, HB1b);
    agg2_k<<<BATCH, WIDTH, 0, stream>>>(nbd, node_idx, M1b, AGG2b);

    // T2 = HB1 @ Wself.T  [4096,128] f32
    mgemm<false, false, false, false, false, false><<<BB, 256, 0, stream>>>(
        HB1b, Wlb, 256, nullptr, nullptr, nullptr, nullptr, T2, BATCH);

    // out = normalize(relu(AGG2 @ Wagg-part.T + T2 + b_lin))  [4096,128] f32
    mgemm<true, true, true, true, false, false><<<BB, 256, 0, stream>>>(
        AGG2b, Wlb + 128, 256, b_lin, T2, nullptr, nullptr, out, BATCH);
}

// Round 3
// 104.352 us; speedup vs baseline: 7.0309x; 1.2246x over previous
//
#include <hip/hip_runtime.h>
#include <math.h>

#define N_NODES 50000
#define DEG 32
#define WIDTH 128
#define BATCH 4096
#define EPS 1e-12f
#define NEG_INF -3.402823466e+38f

typedef __attribute__((ext_vector_type(8))) short short8;   // 8 bf16 (4 VGPRs)
typedef __attribute__((ext_vector_type(4))) float f32x4;    // MFMA accumulator
typedef unsigned short u16;

__device__ __forceinline__ float bf2f(u16 u) {
    unsigned v = ((unsigned)u) << 16;
    float f;
    __builtin_memcpy(&f, &v, 4);
    return f;
}
__device__ __forceinline__ u16 f2bf(float f) {
    unsigned x;
    __builtin_memcpy(&x, &f, 4);
    unsigned r = (x + 0x7fff + ((x >> 16) & 1)) >> 16;  // RNE
    return (u16)r;
}

// ---------------- prep: inv = -1, cvt both weights to bf16 ----------------
__global__ void prep_k(const float* __restrict__ W_agg, const float* __restrict__ W_lin,
                       int* __restrict__ inv, u16* __restrict__ Wab, u16* __restrict__ Wlb) {
    int i = blockIdx.x * 256 + threadIdx.x;
    if (i < 50048) inv[i] = -1;
    int j = i - 50048;
    if (j >= 0 && j < 16384) Wab[j] = f2bf(W_agg[j]);
    int k = i - (50048 + 16384);
    if (k >= 0 && k < 32768) Wlb[k] = f2bf(W_lin[k]);
}

__global__ void scatter_inv_k(const int* __restrict__ node_idx, int* __restrict__ inv) {
    int i = blockIdx.x * blockDim.x + threadIdx.x;
    if (i < BATCH) atomicMax(&inv[node_idx[i]], i);  // last-write-wins == max batch index
}

// ---------------- head: M0b = relu(feats@Wagg.T + b_agg), S = feats@Wself.T ----------------
// 64-row tile, 4 waves, wave w owns rows w*16..+15. f32 A converted inline.
__global__ __launch_bounds__(256) void head_k(
    const float* __restrict__ feats, const u16* __restrict__ Wab, const u16* __restrict__ Wlb,
    const float* __restrict__ b_agg, float* __restrict__ M0b, float* __restrict__ S) {
    int tid = threadIdx.x;
    int w = tid >> 6, l = tid & 63, li = l & 15, kq = l >> 4;
    int row0 = blockIdx.x * 64 + w * 16;
    int arow = row0 + li;  // BATCH is a multiple of 64: always valid

    f32x4 am[8], as[8];
#pragma unroll
    for (int n = 0; n < 8; ++n) { am[n] = (f32x4){0,0,0,0}; as[n] = (f32x4){0,0,0,0}; }

#pragma unroll
    for (int kk = 0; kk < 4; ++kk) {
        float4 a0 = *(const float4*)(feats + (size_t)arow * 128 + kk * 32 + kq * 8);
        float4 a1 = *(const float4*)(feats + (size_t)arow * 128 + kk * 32 + kq * 8 + 4);
        short8 a;
        a[0] = (short)f2bf(a0.x); a[1] = (short)f2bf(a0.y);
        a[2] = (short)f2bf(a0.z); a[3] = (short)f2bf(a0.w);
        a[4] = (short)f2bf(a1.x); a[5] = (short)f2bf(a1.y);
        a[6] = (short)f2bf(a1.z); a[7] = (short)f2bf(a1.w);
#pragma unroll
        for (int n = 0; n < 8; ++n) {
            short8 bm = *(const short8*)(Wab + (size_t)(n * 16 + li) * 128 + kk * 32 + kq * 8);
            am[n] = __builtin_amdgcn_mfma_f32_16x16x32_bf16(a, bm, am[n], 0, 0, 0);
            short8 bs = *(const short8*)(Wlb + (size_t)(n * 16 + li) * 256 + kk * 32 + kq * 8);
            as[n] = __builtin_amdgcn_mfma_f32_16x16x32_bf16(a, bs, as[n], 0, 0, 0);
        }
    }

    float bv[8];
#pragma unroll
    for (int n = 0; n < 8; ++n) bv[n] = b_agg[n * 16 + li];

#pragma unroll
    for (int r = 0; r < 4; ++r) {
        int grow = row0 + kq * 4 + r;
#pragma unroll
        for (int n = 0; n < 8; ++n) {
            M0b[(size_t)grow * 128 + n * 16 + li] = fmaxf(am[n][r] + bv[n], 0.f);
            S[(size_t)grow * 128 + n * 16 + li] = as[n][r];
        }
    }
}

// ---------------- hop1 fused: agg1 gather-max + H1 GEMM + M1 GEMM ----------------
// Per 64-row tile: stage inv-translated neighbor lists, compact warm entries,
// gather-max M0b directly into A-fragment registers, MFMA (Wlin agg-part) with
// S[inv]+bias+relu+norm epilogue, write H1 (warm rows only), LDS-transpose,
// second MFMA (Wagg) -> M1.
__global__ __launch_bounds__(256) void hop1_k(
    const int* __restrict__ nbd, const int* __restrict__ inv,
    const float* __restrict__ M0b, const float* __restrict__ b_agg,
    const float* __restrict__ b_lin, const float* __restrict__ S,
    const u16* __restrict__ Wlb, const u16* __restrict__ Wab,
    u16* __restrict__ H1g, u16* __restrict__ M1) {
    __shared__ int nbi[64 * 32];    // inv-translated neighbor slots
    __shared__ int nbw[64 * 33];    // [r*33]: cnt | anyCold<<16, then warm batch idxs
    __shared__ u16 h1t[64 * 136];   // padded transpose buffer (stride 136 elems = 272 B)

    int tid = threadIdx.x;
    int w = tid >> 6, l = tid & 63, li = l & 15, kq = l >> 4;
    int row0 = blockIdx.x * 64;

    // stage + translate neighbors (coalesced nbd reads, random inv gathers from L2)
#pragma unroll
    for (int s = 0; s < 8; ++s) {
        int idx = tid + s * 256;  // 0..2047
        int node = row0 + (idx >> 5);
        if (node > N_NODES - 1) node = N_NODES - 1;
        nbi[idx] = inv[nbd[(size_t)node * 32 + (idx & 31)]];
    }
    __syncthreads();

    // compact warm lists, one thread per row
    if (tid < 64) {
        int cnt = 0, anyCold = 0;
#pragma unroll
        for (int j = 0; j < 32; ++j) {
            int bi = nbi[tid * 32 + j];
            if (bi >= 0) nbw[tid * 33 + 1 + (cnt++)] = bi;
            else anyCold = 1;
        }
        nbw[tid * 33] = cnt | (anyCold << 16);
    }
    __syncthreads();

    int lrow = w * 16 + li;  // local row this lane gathers / A-frag row
    int info = nbw[lrow * 33];
    int cnt = info & 0xffff, anyCold = info >> 16;

    // gather-max into f32 regs (lane covers cols kk*32 + kq*8 .. +8)
    float acc[4][8];
#pragma unroll
    for (int kk = 0; kk < 4; ++kk) {
        float4 b0 = *(const float4*)(b_agg + kk * 32 + kq * 8);
        float4 b1 = *(const float4*)(b_agg + kk * 32 + kq * 8 + 4);
        float rv[8] = {b0.x, b0.y, b0.z, b0.w, b1.x, b1.y, b1.z, b1.w};
#pragma unroll
        for (int j = 0; j < 8; ++j)
            acc[kk][j] = anyCold ? fmaxf(rv[j], 0.f) : NEG_INF;
    }
    for (int t = 0; t < cnt; ++t) {  // divergent trip count, exec-masked
        int bi = nbw[lrow * 33 + 1 + t];
#pragma unroll
        for (int kk = 0; kk < 4; ++kk) {
            float4 m0 = *(const float4*)(M0b + (size_t)bi * 128 + kk * 32 + kq * 8);
            float4 m1v = *(const float4*)(M0b + (size_t)bi * 128 + kk * 32 + kq * 8 + 4);
            acc[kk][0] = fmaxf(acc[kk][0], m0.x);  acc[kk][1] = fmaxf(acc[kk][1], m0.y);
            acc[kk][2] = fmaxf(acc[kk][2], m0.z);  acc[kk][3] = fmaxf(acc[kk][3], m0.w);
            acc[kk][4] = fmaxf(acc[kk][4], m1v.x); acc[kk][5] = fmaxf(acc[kk][5], m1v.y);
            acc[kk][6] = fmaxf(acc[kk][6], m1v.z); acc[kk][7] = fmaxf(acc[kk][7], m1v.w);
        }
    }

    short8 af[4];
#pragma unroll
    for (int kk = 0; kk < 4; ++kk)
#pragma unroll
        for (int j = 0; j < 8; ++j) af[kk][j] = (short)f2bf(acc[kk][j]);

    // phase-1 MFMA: pre-act H1 = AGG1 @ Wagg-part.T
    f32x4 h[8];
#pragma unroll
    for (int n = 0; n < 8; ++n) h[n] = (f32x4){0,0,0,0};
#pragma unroll
    for (int kk = 0; kk < 4; ++kk)
#pragma unroll
        for (int n = 0; n < 8; ++n) {
            short8 b = *(const short8*)(Wlb + (size_t)(n * 16 + li) * 256 + 128 + kk * 32 + kq * 8);
            h[n] = __builtin_amdgcn_mfma_f32_16x16x32_bf16(af[kk], b, h[n], 0, 0, 0);
        }

    // epilogue 1: +S[inv], +b_lin, relu, row-normalize; write warm H1; stash tile in LDS
    float blv[8];
#pragma unroll
    for (int n = 0; n < 8; ++n) blv[n] = b_lin[n * 16 + li];

#pragma unroll
    for (int r = 0; r < 4; ++r) {
        int lr = w * 16 + kq * 4 + r;
        int grow = row0 + lr;
        int growc = grow < N_NODES ? grow : N_NODES - 1;
        int bi = inv[growc];
        float v[8];
#pragma unroll
        for (int n = 0; n < 8; ++n) v[n] = h[n][r] + blv[n];
        if (bi >= 0) {
#pragma unroll
            for (int n = 0; n < 8; ++n) v[n] += S[(size_t)bi * 128 + n * 16 + li];
        }
#pragma unroll
        for (int n = 0; n < 8; ++n) v[n] = fmaxf(v[n], 0.f);
        float p = 0.f;
#pragma unroll
        for (int n = 0; n < 8; ++n) p += v[n] * v[n];
        p += __shfl_xor(p, 1);
        p += __shfl_xor(p, 2);
        p += __shfl_xor(p, 4);
        p += __shfl_xor(p, 8);
        float sc = 1.0f / fmaxf(sqrtf(p), EPS);
        u16 vb[8];
#pragma unroll
        for (int n = 0; n < 8; ++n) vb[n] = f2bf(v[n] * sc);
        if (grow < N_NODES && bi >= 0) {
#pragma unroll
            for (int n = 0; n < 8; ++n) H1g[(size_t)grow * 128 + n * 16 + li] = vb[n];
        }
#pragma unroll
        for (int n = 0; n < 8; ++n) h1t[lr * 136 + n * 16 + li] = vb[n];
    }
    __syncthreads();

    // phase-2 MFMA: M1 = relu(H1 @ Wagg.T + b_agg)
    short8 af2[4];
#pragma unroll
    for (int kk = 0; kk < 4; ++kk)
        af2[kk] = *(const short8*)(h1t + lrow * 136 + kk * 32 + kq * 8);

    f32x4 m[8];
#pragma unroll
    for (int n = 0; n < 8; ++n) m[n] = (f32x4){0,0,0,0};
#pragma unroll
    for (int kk = 0; kk < 4; ++kk)
#pragma unroll
        for (int n = 0; n < 8; ++n) {
            short8 b = *(const short8*)(Wab + (size_t)(n * 16 + li) * 128 + kk * 32 + kq * 8);
            m[n] = __builtin_amdgcn_mfma_f32_16x16x32_bf16(af2[kk], b, m[n], 0, 0, 0);
        }

    float bav[8];
#pragma unroll
    for (int n = 0; n < 8; ++n) bav[n] = b_agg[n * 16 + li];
#pragma unroll
    for (int r = 0; r < 4; ++r) {
        int grow = row0 + w * 16 + kq * 4 + r;
        if (grow < N_NODES) {
#pragma unroll
            for (int n = 0; n < 8; ++n)
                M1[(size_t)grow * 128 + n * 16 + li] = f2bf(fmaxf(m[n][r] + bav[n], 0.f));
        }
    }
}

// ---------------- tail gather: AB2[i] = [ H1[node_idx[i]] | max_nb M1[nb] ] ----------------
__global__ void tailg_k(const int* __restrict__ nbd, const int* __restrict__ node_idx,
                        const u16* __restrict__ H1g, const u16* __restrict__ M1,
                        u16* __restrict__ AB2) {
    int i = blockIdx.x;
    int t = threadIdx.x;  // 128
    __shared__ int nb[DEG];
    int n = node_idx[i];
    if (t < DEG) nb[t] = nbd[(size_t)n * 32 + t];
    AB2[(size_t)i * 256 + t] = H1g[(size_t)n * 128 + t];
    __syncthreads();
    float acc = NEG_INF;
#pragma unroll
    for (int j = 0; j < DEG; ++j) acc = fmaxf(acc, bf2f(M1[(size_t)nb[j] * 128 + t]));
    AB2[(size_t)i * 256 + 128 + t] = f2bf(acc);
}

// ---------------- tail GEMM: out = norm(relu(AB2 @ W_lin.T + b_lin)), K=256 ----------------
__global__ __launch_bounds__(256) void tail_k(
    const u16* __restrict__ AB2, const u16* __restrict__ Wlb,
    const float* __restrict__ b_lin, float* __restrict__ out) {
    int tid = threadIdx.x;
    int w = tid >> 6, l = tid & 63, li = l & 15, kq = l >> 4;
    int row0 = blockIdx.x * 64 + w * 16;
    int arow = row0 + li;

    f32x4 acc[8];
#pragma unroll
    for (int n = 0; n < 8; ++n) acc[n] = (f32x4){0,0,0,0};

#pragma unroll
    for (int kk = 0; kk < 8; ++kk) {
        short8 a = *(const short8*)(AB2 + (size_t)arow * 256 + kk * 32 + kq * 8);
#pragma unroll
        for (int n = 0; n < 8; ++n) {
            short8 b = *(const short8*)(Wlb + (size_t)(n * 16 + li) * 256 + kk * 32 + kq * 8);
            acc[n] = __builtin_amdgcn_mfma_f32_16x16x32_bf16(a, b, acc[n], 0, 0, 0);
        }
    }

    float blv[8];
#pragma unroll
    for (int n = 0; n < 8; ++n) blv[n] = b_lin[n * 16 + li];

#pragma unroll
    for (int r = 0; r < 4; ++r) {
        int grow = row0 + kq * 4 + r;
        float v[8];
#pragma unroll
        for (int n = 0; n < 8; ++n) v[n] = fmaxf(acc[n][r] + blv[n], 0.f);
        float p = 0.f;
#pragma unroll
        for (int n = 0; n < 8; ++n) p += v[n] * v[n];
        p += __shfl_xor(p, 1);
        p += __shfl_xor(p, 2);
        p += __shfl_xor(p, 4);
        p += __shfl_xor(p, 8);
        float sc = 1.0f / fmaxf(sqrtf(p), EPS);
#pragma unroll
        for (int n = 0; n < 8; ++n) out[(size_t)grow * 128 + n * 16 + li] = v[n] * sc;
    }
}

// ---------------- launch ----------------
extern "C" void kernel_launch(void* const* d_in, const int* in_sizes, int n_in,
                              void* d_out, int out_size, void* d_ws, size_t ws_size,
                              hipStream_t stream) {
    const int*   nbd      = (const int*)d_in[0];
    const int*   node_idx = (const int*)d_in[1];
    const float* feats    = (const float*)d_in[2];
    const float* W_agg    = (const float*)d_in[3];
    const float* b_agg    = (const float*)d_in[4];
    const float* W_lin    = (const float*)d_in[5];
    const float* b_lin    = (const float*)d_in[6];
    float* out = (float*)d_out;

    char* base = (char*)d_ws;
    size_t off = 0;
    int* inv  = (int*)(base + off); off += 50048 * 4;
    u16* Wab  = (u16*)(base + off); off += 16384 * 2;
    u16* Wlb  = (u16*)(base + off); off += 32768 * 2;
    float* M0b = (float*)(base + off); off += (size_t)BATCH * 128 * 4;
    float* S   = (float*)(base + off); off += (size_t)BATCH * 128 * 4;
    u16* H1g  = (u16*)(base + off); off += (size_t)N_NODES * 128 * 2;
    u16* M1   = (u16*)(base + off); off += (size_t)N_NODES * 128 * 2;
    u16* AB2  = (u16*)(base + off); off += (size_t)BATCH * 256 * 2;

    const int GB = (N_NODES + 63) / 64;  // 782
    const int BB = BATCH / 64;           // 64

    prep_k<<<(50048 + 16384 + 32768 + 255) / 256, 256, 0, stream>>>(W_agg, W_lin, inv, Wab, Wlb);
    scatter_inv_k<<<(BATCH + 255) / 256, 256, 0, stream>>>(node_idx, inv);

    head_k<<<BB, 256, 0, stream>>>(feats, Wab, Wlb, b_agg, M0b, S);

    hop1_k<<<GB, 256, 0, stream>>>(nbd, inv, M0b, b_agg, b_lin, S, Wlb, Wab, H1g, M1);

    tailg_k<<<BATCH, 128, 0, stream>>>(nbd, node_idx, H1g, M1, AB2);

    tail_k<<<BB, 256, 0, stream>>>(AB2, Wlb, b_lin, out);
}

// Round 4
// 87.262 us; speedup vs baseline: 8.4080x; 1.1959x over previous
//
#include <hip/hip_runtime.h>
#include <math.h>

#define N_NODES 50000
#define DEG 32
#define WIDTH 128
#define BATCH 4096
#define EPS 1e-12f

typedef __attribute__((ext_vector_type(8))) short short8;           // 8 bf16
typedef __attribute__((ext_vector_type(8))) unsigned short ushort8; // 8 bf16 as u16
typedef __attribute__((ext_vector_type(4))) float f32x4;            // MFMA acc
typedef unsigned short u16;

__device__ __forceinline__ float bf2f(u16 u) {
    unsigned v = ((unsigned)u) << 16;
    float f;
    __builtin_memcpy(&f, &v, 4);
    return f;
}
__device__ __forceinline__ u16 f2bf(float f) {
    unsigned x;
    __builtin_memcpy(&x, &f, 4);
    unsigned r = (x + 0x7fff + ((x >> 16) & 1)) >> 16;  // RNE
    return (u16)r;
}
__device__ __forceinline__ ushort8 umax8(ushort8 a, ushort8 b) {
#pragma unroll
    for (int j = 0; j < 8; ++j) a[j] = a[j] > b[j] ? a[j] : b[j];
    return a;
}
__device__ __forceinline__ short8 as_s8(ushort8 a) {
    short8 r;
    __builtin_memcpy(&r, &a, 16);
    return r;
}

// ---------------- prep: inv = -1, cvt both weights to bf16 ----------------
__global__ void prep_k(const float* __restrict__ W_agg, const float* __restrict__ W_lin,
                       int* __restrict__ inv, u16* __restrict__ Wab, u16* __restrict__ Wlb) {
    int i = blockIdx.x * 256 + threadIdx.x;
    if (i < 50048) inv[i] = -1;
    int j = i - 50048;
    if (j >= 0 && j < 16384) Wab[j] = f2bf(W_agg[j]);
    int k = i - (50048 + 16384);
    if (k >= 0 && k < 32768) Wlb[k] = f2bf(W_lin[k]);
}

// ---------------- head: scatter inv; M0b(bf16) = relu(feats@Wagg.T+b_agg); S(f32) = feats@Wself.T
// 256 blocks x 256 thr; block owns 16 rows; wave w owns cols w*32..+31 (2 frags).
__global__ __launch_bounds__(256) void head_k(
    const float* __restrict__ feats, const u16* __restrict__ Wab, const u16* __restrict__ Wlb,
    const float* __restrict__ b_agg, const int* __restrict__ node_idx, int* __restrict__ inv,
    u16* __restrict__ M0b, float* __restrict__ S) {
    int tid = threadIdx.x;
    int gid = blockIdx.x * 256 + tid;
    if (gid < BATCH) atomicMax(&inv[node_idx[gid]], gid);  // last-write-wins scatter

    int w = tid >> 6, l = tid & 63, li = l & 15, kq = l >> 4;
    int r0 = blockIdx.x * 16;
    int arow = r0 + li;   // 256*16 == BATCH: always valid
    int c0 = w * 32;

    f32x4 am[2], as[2];
#pragma unroll
    for (int n = 0; n < 2; ++n) { am[n] = (f32x4){0,0,0,0}; as[n] = (f32x4){0,0,0,0}; }

#pragma unroll
    for (int kk = 0; kk < 4; ++kk) {
        float4 a0 = *(const float4*)(feats + (size_t)arow * 128 + kk * 32 + kq * 8);
        float4 a1 = *(const float4*)(feats + (size_t)arow * 128 + kk * 32 + kq * 8 + 4);
        short8 a;
        a[0] = (short)f2bf(a0.x); a[1] = (short)f2bf(a0.y);
        a[2] = (short)f2bf(a0.z); a[3] = (short)f2bf(a0.w);
        a[4] = (short)f2bf(a1.x); a[5] = (short)f2bf(a1.y);
        a[6] = (short)f2bf(a1.z); a[7] = (short)f2bf(a1.w);
#pragma unroll
        for (int n = 0; n < 2; ++n) {
            int col = c0 + n * 16 + li;
            short8 bm = *(const short8*)(Wab + (size_t)col * 128 + kk * 32 + kq * 8);
            am[n] = __builtin_amdgcn_mfma_f32_16x16x32_bf16(a, bm, am[n], 0, 0, 0);
            short8 bs = *(const short8*)(Wlb + (size_t)col * 256 + kk * 32 + kq * 8);
            as[n] = __builtin_amdgcn_mfma_f32_16x16x32_bf16(a, bs, as[n], 0, 0, 0);
        }
    }

#pragma unroll
    for (int r = 0; r < 4; ++r) {
        int grow = r0 + kq * 4 + r;
#pragma unroll
        for (int n = 0; n < 2; ++n) {
            int col = c0 + n * 16 + li;
            float t = am[n][r] + b_agg[col];
            t = t > 0.f ? t : 0.f;               // relu with guaranteed +0 (u16-max safety)
            M0b[(size_t)grow * 128 + col] = f2bf(t);
            S[(size_t)grow * 128 + col] = as[n][r];
        }
    }
}

// ---------------- hop1 fused: ballot-compacted gather-max + H1 GEMM + M1 GEMM ----------------
__global__ __launch_bounds__(256, 6) void hop1_k(
    const int* __restrict__ nbd, const int* __restrict__ inv,
    const u16* __restrict__ M0b, const float* __restrict__ b_agg,
    const float* __restrict__ b_lin, const float* __restrict__ S,
    const u16* __restrict__ Wlb, const u16* __restrict__ Wab,
    u16* __restrict__ H1g, u16* __restrict__ M1) {
    __shared__ int nbi[64 * 33];    // padded: conflict-free column access
    __shared__ int meta[64];        // cnt | anyCold<<16
    __shared__ int rowinv[64];      // inv[] for the tile's own rows
    __shared__ u16 h1t[64 * 136];   // transpose buffer (stride 272 B)

    int tid = threadIdx.x;
    int w = tid >> 6, l = tid & 63, li = l & 15, kq = l >> 4;
    int row0 = blockIdx.x * 64;

    // stage translated neighbors (coalesced nbd, random inv gathers)
#pragma unroll
    for (int s = 0; s < 8; ++s) {
        int idx = tid + s * 256;  // 0..2047
        int r = idx >> 5, j = idx & 31;
        int node = row0 + r;
        if (node > N_NODES - 1) node = N_NODES - 1;
        nbi[r * 33 + j] = inv[nbd[(size_t)node * 32 + j]];
    }
    if (tid < 64) {
        int node = row0 + tid;
        if (node > N_NODES - 1) node = N_NODES - 1;
        rowinv[tid] = inv[node];
    }
    __syncthreads();

    // ballot-parallel compaction: half-wave per row, 8 rounds
    {
        int hw = tid >> 5, lane32 = tid & 31;
#pragma unroll
        for (int rr = 0; rr < 8; ++rr) {
            int r = hw + rr * 8;
            int bi = nbi[r * 33 + lane32];
            unsigned long long bm = __ballot(bi >= 0);
            unsigned mask32 = (tid & 32) ? (unsigned)(bm >> 32) : (unsigned)bm;
            if (bi >= 0) {
                int pos = __popc(mask32 & ((1u << lane32) - 1));
                nbi[r * 33 + pos] = bi;  // wave-lockstep: all reads precede writes
            }
            if (lane32 == 0) meta[r] = __popc(mask32) | ((mask32 != 0xffffffffu) << 16);
        }
    }
    __syncthreads();

    int lrow = w * 16 + li;
    int info = meta[lrow];
    int cnt = info & 0xffff, anyCold = info >> 16;

    // gather-max in bf16/u16 domain (all values >= +0): acc IS the A-fragment
    ushort8 acc[4];
#pragma unroll
    for (int kk = 0; kk < 4; ++kk) {
        float4 b0 = *(const float4*)(b_agg + kk * 32 + kq * 8);
        float4 b1 = *(const float4*)(b_agg + kk * 32 + kq * 8 + 4);
        float rv[8] = {b0.x, b0.y, b0.z, b0.w, b1.x, b1.y, b1.z, b1.w};
#pragma unroll
        for (int j = 0; j < 8; ++j) {
            float t = rv[j] > 0.f ? rv[j] : 0.f;
            acc[kk][j] = anyCold ? f2bf(t) : (u16)0;
        }
    }
    for (int t = 0; t < cnt; ++t) {  // exec-masked, trip = max warm count in wave
        int bi = nbi[lrow * 33 + t];
#pragma unroll
        for (int kk = 0; kk < 4; ++kk) {
            ushort8 v = *(const ushort8*)(M0b + (size_t)bi * 128 + kk * 32 + kq * 8);
            acc[kk] = umax8(acc[kk], v);
        }
    }

    // phase-1 MFMA: pre-act H1 = AGG1 @ Wagg-part.T
    f32x4 h[8];
#pragma unroll
    for (int n = 0; n < 8; ++n) h[n] = (f32x4){0,0,0,0};
#pragma unroll
    for (int kk = 0; kk < 4; ++kk) {
        short8 a = as_s8(acc[kk]);
#pragma unroll
        for (int n = 0; n < 8; ++n) {
            short8 b = *(const short8*)(Wlb + (size_t)(n * 16 + li) * 256 + 128 + kk * 32 + kq * 8);
            h[n] = __builtin_amdgcn_mfma_f32_16x16x32_bf16(a, b, h[n], 0, 0, 0);
        }
    }

    // epilogue 1: +S[inv], +b_lin, relu, row-normalize; write warm H1; stash tile
    float blv[8];
#pragma unroll
    for (int n = 0; n < 8; ++n) blv[n] = b_lin[n * 16 + li];

#pragma unroll
    for (int r = 0; r < 4; ++r) {
        int lr = w * 16 + kq * 4 + r;
        int grow = row0 + lr;
        int bi = rowinv[lr];
        float v[8];
#pragma unroll
        for (int n = 0; n < 8; ++n) v[n] = h[n][r] + blv[n];
        if (bi >= 0) {
#pragma unroll
            for (int n = 0; n < 8; ++n) v[n] += S[(size_t)bi * 128 + n * 16 + li];
        }
#pragma unroll
        for (int n = 0; n < 8; ++n) v[n] = fmaxf(v[n], 0.f);
        float p = 0.f;
#pragma unroll
        for (int n = 0; n < 8; ++n) p += v[n] * v[n];
        p += __shfl_xor(p, 1);
        p += __shfl_xor(p, 2);
        p += __shfl_xor(p, 4);
        p += __shfl_xor(p, 8);
        float sc = 1.0f / fmaxf(sqrtf(p), EPS);
        u16 vb[8];
#pragma unroll
        for (int n = 0; n < 8; ++n) vb[n] = f2bf(v[n] * sc);
        if (grow < N_NODES && bi >= 0) {
#pragma unroll
            for (int n = 0; n < 8; ++n) H1g[(size_t)grow * 128 + n * 16 + li] = vb[n];
        }
#pragma unroll
        for (int n = 0; n < 8; ++n) h1t[lr * 136 + n * 16 + li] = vb[n];
    }
    __syncthreads();

    // phase-2 MFMA: M1 = relu(H1 @ Wagg.T + b_agg)
    short8 af2[4];
#pragma unroll
    for (int kk = 0; kk < 4; ++kk)
        af2[kk] = *(const short8*)(h1t + lrow * 136 + kk * 32 + kq * 8);

    f32x4 m[8];
#pragma unroll
    for (int n = 0; n < 8; ++n) m[n] = (f32x4){0,0,0,0};
#pragma unroll
    for (int kk = 0; kk < 4; ++kk)
#pragma unroll
        for (int n = 0; n < 8; ++n) {
            short8 b = *(const short8*)(Wab + (size_t)(n * 16 + li) * 128 + kk * 32 + kq * 8);
            m[n] = __builtin_amdgcn_mfma_f32_16x16x32_bf16(af2[kk], b, m[n], 0, 0, 0);
        }

    float bav[8];
#pragma unroll
    for (int n = 0; n < 8; ++n) bav[n] = b_agg[n * 16 + li];
#pragma unroll
    for (int r = 0; r < 4; ++r) {
        int grow = row0 + w * 16 + kq * 4 + r;
        if (grow < N_NODES) {
#pragma unroll
            for (int n = 0; n < 8; ++n) {
                float t = m[n][r] + bav[n];
                t = t > 0.f ? t : 0.f;  // +0-safe relu (M1 feeds u16-max in tailg)
                M1[(size_t)grow * 128 + n * 16 + li] = f2bf(t);
            }
        }
    }
}

// ---------------- tail gather: AB2[i] = [ H1[node_idx[i]] | max_nb M1[nb] ] (u16 max) ----------------
__global__ void tailg_k(const int* __restrict__ nbd, const int* __restrict__ node_idx,
                        const u16* __restrict__ H1g, const u16* __restrict__ M1,
                        u16* __restrict__ AB2) {
    int i = blockIdx.x;
    int t = threadIdx.x;  // 128
    __shared__ int nb[DEG];
    int n = node_idx[i];
    if (t < DEG) nb[t] = nbd[(size_t)n * 32 + t];
    AB2[(size_t)i * 256 + t] = H1g[(size_t)n * 128 + t];
    __syncthreads();
    u16 acc = 0;  // all M1 values >= +0
#pragma unroll
    for (int j = 0; j < DEG; ++j) {
        u16 v = M1[(size_t)nb[j] * 128 + t];
        acc = v > acc ? v : acc;
    }
    AB2[(size_t)i * 256 + 128 + t] = acc;
}

// ---------------- tail GEMM: out = norm(relu(AB2 @ W_lin.T + b_lin)), K=256 ----------------
// 128 blocks x 128 thr; wave owns 16 full rows.
__global__ __launch_bounds__(128) void tail_k(
    const u16* __restrict__ AB2, const u16* __restrict__ Wlb,
    const float* __restrict__ b_lin, float* __restrict__ out) {
    int tid = threadIdx.x;
    int w = tid >> 6, l = tid & 63, li = l & 15, kq = l >> 4;
    int row0 = blockIdx.x * 32 + w * 16;
    int arow = row0 + li;

    f32x4 acc[8];
#pragma unroll
    for (int n = 0; n < 8; ++n) acc[n] = (f32x4){0,0,0,0};

#pragma unroll
    for (int kk = 0; kk < 8; ++kk) {
        short8 a = *(const short8*)(AB2 + (size_t)arow * 256 + kk * 32 + kq * 8);
#pragma unroll
        for (int n = 0; n < 8; ++n) {
            short8 b = *(const short8*)(Wlb + (size_t)(n * 16 + li) * 256 + kk * 32 + kq * 8);
            acc[n] = __builtin_amdgcn_mfma_f32_16x16x32_bf16(a, b, acc[n], 0, 0, 0);
        }
    }

    float blv[8];
#pragma unroll
    for (int n = 0; n < 8; ++n) blv[n] = b_lin[n * 16 + li];

#pragma unroll
    for (int r = 0; r < 4; ++r) {
        int grow = row0 + kq * 4 + r;
        float v[8];
#pragma unroll
        for (int n = 0; n < 8; ++n) v[n] = fmaxf(acc[n][r] + blv[n], 0.f);
        float p = 0.f;
#pragma unroll
        for (int n = 0; n < 8; ++n) p += v[n] * v[n];
        p += __shfl_xor(p, 1);
        p += __shfl_xor(p, 2);
        p += __shfl_xor(p, 4);
        p += __shfl_xor(p, 8);
        float sc = 1.0f / fmaxf(sqrtf(p), EPS);
#pragma unroll
        for (int n = 0; n < 8; ++n) out[(size_t)grow * 128 + n * 16 + li] = v[n] * sc;
    }
}

// ---------------- launch ----------------
extern "C" void kernel_launch(void* const* d_in, const int* in_sizes, int n_in,
                              void* d_out, int out_size, void* d_ws, size_t ws_size,
                              hipStream_t stream) {
    const int*   nbd      = (const int*)d_in[0];
    const int*   node_idx = (const int*)d_in[1];
    const float* feats    = (const float*)d_in[2];
    const float* W_agg    = (const float*)d_in[3];
    const float* b_agg    = (const float*)d_in[4];
    const float* W_lin    = (const float*)d_in[5];
    const float* b_lin    = (const float*)d_in[6];
    float* out = (float*)d_out;

    char* base = (char*)d_ws;
    size_t off = 0;
    int* inv  = (int*)(base + off); off += 50048 * 4;
    u16* Wab  = (u16*)(base + off); off += 16384 * 2;
    u16* Wlb  = (u16*)(base + off); off += 32768 * 2;
    u16* M0b  = (u16*)(base + off); off += (size_t)BATCH * 128 * 2;
    float* S  = (float*)(base + off); off += (size_t)BATCH * 128 * 4;
    u16* H1g  = (u16*)(base + off); off += (size_t)N_NODES * 128 * 2;
    u16* M1   = (u16*)(base + off); off += (size_t)N_NODES * 128 * 2;
    u16* AB2  = (u16*)(base + off); off += (size_t)BATCH * 256 * 2;

    const int GB = (N_NODES + 63) / 64;  // 782

    prep_k<<<(50048 + 16384 + 32768 + 255) / 256, 256, 0, stream>>>(W_agg, W_lin, inv, Wab, Wlb);

    head_k<<<BATCH / 16, 256, 0, stream>>>(feats, Wab, Wlb, b_agg, node_idx, inv, M0b, S);

    hop1_k<<<GB, 256, 0, stream>>>(nbd, inv, M0b, b_agg, b_lin, S, Wlb, Wab, H1g, M1);

    tailg_k<<<BATCH, 128, 0, stream>>>(nbd, node_idx, H1g, M1, AB2);

    tail_k<<<BATCH / 32, 128, 0, stream>>>(AB2, Wlb, b_lin, out);
}

// Round 5
// 79.381 us; speedup vs baseline: 9.2427x; 1.0993x over previous
//
#include <hip/hip_runtime.h>
#include <math.h>

#define N_NODES 50000
#define DEG 32
#define WIDTH 128
#define BATCH 4096
#define EPS 1e-12f

typedef __attribute__((ext_vector_type(8))) short short8;           // 8 bf16
typedef __attribute__((ext_vector_type(8))) unsigned short ushort8; // 8 bf16 as u16
typedef __attribute__((ext_vector_type(4))) float f32x4;            // MFMA acc
typedef unsigned short u16;

__device__ __forceinline__ float bf2f(u16 u) {
    unsigned v = ((unsigned)u) << 16;
    float f;
    __builtin_memcpy(&f, &v, 4);
    return f;
}
__device__ __forceinline__ u16 f2bf(float f) {
    unsigned x;
    __builtin_memcpy(&x, &f, 4);
    unsigned r = (x + 0x7fff + ((x >> 16) & 1)) >> 16;  // RNE
    return (u16)r;
}
__device__ __forceinline__ ushort8 umax8(ushort8 a, ushort8 b) {
#pragma unroll
    for (int j = 0; j < 8; ++j) a[j] = a[j] > b[j] ? a[j] : b[j];
    return a;
}
__device__ __forceinline__ short8 as_s8(ushort8 a) {
    short8 r;
    __builtin_memcpy(&r, &a, 16);
    return r;
}

// ---------------- prep: inv = -1, cvt both weights to bf16 ----------------
__global__ void prep_k(const float* __restrict__ W_agg, const float* __restrict__ W_lin,
                       int* __restrict__ inv, u16* __restrict__ Wab, u16* __restrict__ Wlb) {
    int i = blockIdx.x * 256 + threadIdx.x;
    if (i < 50048) inv[i] = -1;
    int j = i - 50048;
    if (j >= 0 && j < 16384) Wab[j] = f2bf(W_agg[j]);
    int k = i - (50048 + 16384);
    if (k >= 0 && k < 32768) Wlb[k] = f2bf(W_lin[k]);
}

// ---------------- head: scatter inv; M0b(bf16) = relu(feats@Wagg.T+b_agg); S(f32) = feats@Wself.T
// 256 blocks x 512 thr (8 waves); block owns 16 rows; wave w owns cols w*16..+15.
__global__ __launch_bounds__(512) void head_k(
    const float* __restrict__ feats, const u16* __restrict__ Wab, const u16* __restrict__ Wlb,
    const float* __restrict__ b_agg, const int* __restrict__ node_idx, int* __restrict__ inv,
    u16* __restrict__ M0b, float* __restrict__ S) {
    int tid = threadIdx.x;
    int gid = blockIdx.x * 512 + tid;
    if (gid < BATCH) atomicMax(&inv[node_idx[gid]], gid);  // last-write-wins scatter

    int w = tid >> 6, l = tid & 63, li = l & 15, kq = l >> 4;
    int r0 = blockIdx.x * 16;
    int arow = r0 + li;       // 256*16 == BATCH: always valid
    int col = w * 16 + li;

    f32x4 am = (f32x4){0,0,0,0}, as = (f32x4){0,0,0,0};

#pragma unroll
    for (int kk = 0; kk < 4; ++kk) {
        float4 a0 = *(const float4*)(feats + (size_t)arow * 128 + kk * 32 + kq * 8);
        float4 a1 = *(const float4*)(feats + (size_t)arow * 128 + kk * 32 + kq * 8 + 4);
        short8 a;
        a[0] = (short)f2bf(a0.x); a[1] = (short)f2bf(a0.y);
        a[2] = (short)f2bf(a0.z); a[3] = (short)f2bf(a0.w);
        a[4] = (short)f2bf(a1.x); a[5] = (short)f2bf(a1.y);
        a[6] = (short)f2bf(a1.z); a[7] = (short)f2bf(a1.w);
        short8 bm = *(const short8*)(Wab + (size_t)col * 128 + kk * 32 + kq * 8);
        am = __builtin_amdgcn_mfma_f32_16x16x32_bf16(a, bm, am, 0, 0, 0);
        short8 bs = *(const short8*)(Wlb + (size_t)col * 256 + kk * 32 + kq * 8);
        as = __builtin_amdgcn_mfma_f32_16x16x32_bf16(a, bs, as, 0, 0, 0);
    }

    float ba = b_agg[col];
#pragma unroll
    for (int r = 0; r < 4; ++r) {
        int grow = r0 + kq * 4 + r;
        float t = am[r] + ba;
        t = t > 0.f ? t : 0.f;               // relu with guaranteed +0 (u16-max safety)
        M0b[(size_t)grow * 128 + col] = f2bf(t);
        S[(size_t)grow * 128 + col] = as[r];
    }
}

// ---------------- hop1 fused v3: 32-row tile, 4 waves = 2 row-groups x 2 col-groups ----------------
__global__ __launch_bounds__(256, 6) void hop1_k(
    const int* __restrict__ nbd, const int* __restrict__ inv,
    const u16* __restrict__ M0b, const float* __restrict__ b_agg,
    const float* __restrict__ b_lin, const float* __restrict__ S,
    const u16* __restrict__ Wlb, const u16* __restrict__ Wab,
    u16* __restrict__ H1g, u16* __restrict__ M1) {
    __shared__ int nbi[32 * 33];    // padded: conflict-free column access
    __shared__ int meta[32];        // cnt | anyCold<<16
    __shared__ int rowinv[32];      // inv[] for the tile's own rows
    __shared__ u16 h1t[32 * 136];   // transpose buffer
    __shared__ float pnorm[64];     // [cg][row32] partial row-norms

    int tid = threadIdx.x;
    int w = tid >> 6, l = tid & 63, li = l & 15, kq = l >> 4;
    int rg = w >> 1, cg = w & 1;
    int row0 = blockIdx.x * 32;

    // stage translated neighbors (coalesced nbd, random inv gathers)
#pragma unroll
    for (int s = 0; s < 4; ++s) {
        int idx = tid + s * 256;  // 0..1023
        int r = idx >> 5, j = idx & 31;
        int node = row0 + r;
        if (node > N_NODES - 1) node = N_NODES - 1;
        nbi[r * 33 + j] = inv[nbd[(size_t)node * 32 + j]];
    }
    if (tid < 32) {
        int node = row0 + tid;
        if (node > N_NODES - 1) node = N_NODES - 1;
        rowinv[tid] = inv[node];
    }
    __syncthreads();

    // ballot-parallel compaction: half-wave per row, 4 rounds
    {
        int hw = tid >> 5, lane32 = tid & 31;
#pragma unroll
        for (int rr = 0; rr < 4; ++rr) {
            int r = hw + rr * 8;
            int bi = nbi[r * 33 + lane32];
            unsigned long long bm = __ballot(bi >= 0);
            unsigned mask32 = (tid & 32) ? (unsigned)(bm >> 32) : (unsigned)bm;
            if (bi >= 0) {
                int pos = __popc(mask32 & ((1u << lane32) - 1));
                nbi[r * 33 + pos] = bi;  // wave-lockstep: all reads precede writes
            }
            if (lane32 == 0) meta[r] = __popc(mask32) | ((mask32 != 0xffffffffu) << 16);
        }
    }
    __syncthreads();

    int lrow = rg * 16 + li;           // A-frag row (within 32-tile)
    int info = meta[lrow];
    int cnt = info & 0xffff, anyCold = info >> 16;

    // gather-max in bf16/u16 domain (values >= +0): acc IS the A-fragment
    // (duplicated across the cg pair; extra L2 traffic is cheap vs latency)
    ushort8 acc[4];
#pragma unroll
    for (int kk = 0; kk < 4; ++kk) {
        float4 b0 = *(const float4*)(b_agg + kk * 32 + kq * 8);
        float4 b1 = *(const float4*)(b_agg + kk * 32 + kq * 8 + 4);
        float rv[8] = {b0.x, b0.y, b0.z, b0.w, b1.x, b1.y, b1.z, b1.w};
#pragma unroll
        for (int j = 0; j < 8; ++j) {
            float t = rv[j] > 0.f ? rv[j] : 0.f;
            acc[kk][j] = anyCold ? f2bf(t) : (u16)0;
        }
    }
    for (int t = 0; t < cnt; ++t) {  // exec-masked, trip = max warm count in wave
        int bi = nbi[lrow * 33 + t];
#pragma unroll
        for (int kk = 0; kk < 4; ++kk) {
            ushort8 v = *(const ushort8*)(M0b + (size_t)bi * 128 + kk * 32 + kq * 8);
            acc[kk] = umax8(acc[kk], v);
        }
    }

    // phase-1 MFMA: pre-act H1 = AGG1 @ Wagg-part.T  (4 col-frags = 64 cols)
    f32x4 h[4];
#pragma unroll
    for (int n = 0; n < 4; ++n) h[n] = (f32x4){0,0,0,0};
#pragma unroll
    for (int kk = 0; kk < 4; ++kk) {
        short8 a = as_s8(acc[kk]);
#pragma unroll
        for (int n = 0; n < 4; ++n) {
            int col = cg * 64 + n * 16 + li;
            short8 b = *(const short8*)(Wlb + (size_t)col * 256 + 128 + kk * 32 + kq * 8);
            h[n] = __builtin_amdgcn_mfma_f32_16x16x32_bf16(a, b, h[n], 0, 0, 0);
        }
    }

    // epilogue 1a: +S[inv], +b_lin, relu; partial row-norm -> LDS
    float blv[4];
#pragma unroll
    for (int n = 0; n < 4; ++n) blv[n] = b_lin[cg * 64 + n * 16 + li];

    float v[4][4];  // [r][n], all indices compile-time
#pragma unroll
    for (int r = 0; r < 4; ++r) {
        int lr32 = rg * 16 + kq * 4 + r;
        int bi = rowinv[lr32];
#pragma unroll
        for (int n = 0; n < 4; ++n) v[r][n] = h[n][r] + blv[n];
        if (bi >= 0) {
#pragma unroll
            for (int n = 0; n < 4; ++n)
                v[r][n] += S[(size_t)bi * 128 + cg * 64 + n * 16 + li];
        }
        float p = 0.f;
#pragma unroll
        for (int n = 0; n < 4; ++n) {
            v[r][n] = fmaxf(v[r][n], 0.f);
            p += v[r][n] * v[r][n];
        }
        p += __shfl_xor(p, 1);
        p += __shfl_xor(p, 2);
        p += __shfl_xor(p, 4);
        p += __shfl_xor(p, 8);
        if (li == 0) pnorm[cg * 32 + lr32] = p;
    }
    __syncthreads();

    // epilogue 1b: combine partials, scale, write warm H1 + stash tile
#pragma unroll
    for (int r = 0; r < 4; ++r) {
        int lr32 = rg * 16 + kq * 4 + r;
        int grow = row0 + lr32;
        int bi = rowinv[lr32];
        float p = pnorm[lr32] + pnorm[32 + lr32];
        float sc = 1.0f / fmaxf(sqrtf(p), EPS);
        u16 vb[4];
#pragma unroll
        for (int n = 0; n < 4; ++n) vb[n] = f2bf(v[r][n] * sc);
        if (grow < N_NODES && bi >= 0) {
#pragma unroll
            for (int n = 0; n < 4; ++n)
                H1g[(size_t)grow * 128 + cg * 64 + n * 16 + li] = vb[n];
        }
#pragma unroll
        for (int n = 0; n < 4; ++n) h1t[lr32 * 136 + cg * 64 + n * 16 + li] = vb[n];
    }
    __syncthreads();

    // phase-2 MFMA: M1 = relu(H1 @ Wagg.T + b_agg)
    short8 af2[4];
#pragma unroll
    for (int kk = 0; kk < 4; ++kk)
        af2[kk] = *(const short8*)(h1t + lrow * 136 + kk * 32 + kq * 8);

    f32x4 m[4];
#pragma unroll
    for (int n = 0; n < 4; ++n) m[n] = (f32x4){0,0,0,0};
#pragma unroll
    for (int kk = 0; kk < 4; ++kk)
#pragma unroll
        for (int n = 0; n < 4; ++n) {
            int col = cg * 64 + n * 16 + li;
            short8 b = *(const short8*)(Wab + (size_t)col * 128 + kk * 32 + kq * 8);
            m[n] = __builtin_amdgcn_mfma_f32_16x16x32_bf16(af2[kk], b, m[n], 0, 0, 0);
        }

    float bav[4];
#pragma unroll
    for (int n = 0; n < 4; ++n) bav[n] = b_agg[cg * 64 + n * 16 + li];
#pragma unroll
    for (int r = 0; r < 4; ++r) {
        int grow = row0 + rg * 16 + kq * 4 + r;
        if (grow < N_NODES) {
#pragma unroll
            for (int n = 0; n < 4; ++n) {
                float t = m[n][r] + bav[n];
                t = t > 0.f ? t : 0.f;  // +0-safe relu (M1 feeds u16-max in tailg)
                M1[(size_t)grow * 128 + cg * 64 + n * 16 + li] = f2bf(t);
            }
        }
    }
}

// ---------------- tail gather: AB2[i] = [ H1[node_idx[i]] | max_nb M1[nb] ] (u16 max) ----------------
__global__ void tailg_k(const int* __restrict__ nbd, const int* __restrict__ node_idx,
                        const u16* __restrict__ H1g, const u16* __restrict__ M1,
                        u16* __restrict__ AB2) {
    int i = blockIdx.x;
    int t = threadIdx.x;  // 128
    __shared__ int nb[DEG];
    int n = node_idx[i];
    if (t < DEG) nb[t] = nbd[(size_t)n * 32 + t];
    AB2[(size_t)i * 256 + t] = H1g[(size_t)n * 128 + t];
    __syncthreads();
    u16 acc = 0;  // all M1 values >= +0
#pragma unroll
    for (int j = 0; j < DEG; ++j) {
        u16 v = M1[(size_t)nb[j] * 128 + t];
        acc = v > acc ? v : acc;
    }
    AB2[(size_t)i * 256 + 128 + t] = acc;
}

// ---------------- tail GEMM: out = norm(relu(AB2 @ W_lin.T + b_lin)), K=256 ----------------
// 256 blocks x 512 thr (8 waves); block owns 16 rows; wave w owns cols w*16..+15.
__global__ __launch_bounds__(512) void tail_k(
    const u16* __restrict__ AB2, const u16* __restrict__ Wlb,
    const float* __restrict__ b_lin, float* __restrict__ out) {
    __shared__ float pn[128];   // [w][row16]
    __shared__ float pnt[16];
    int tid = threadIdx.x;
    int w = tid >> 6, l = tid & 63, li = l & 15, kq = l >> 4;
    int row0 = blockIdx.x * 16;
    int arow = row0 + li;
    int col = w * 16 + li;

    f32x4 acc = (f32x4){0,0,0,0};
#pragma unroll
    for (int kk = 0; kk < 8; ++kk) {
        short8 a = *(const short8*)(AB2 + (size_t)arow * 256 + kk * 32 + kq * 8);
        short8 b = *(const short8*)(Wlb + (size_t)col * 256 + kk * 32 + kq * 8);
        acc = __builtin_amdgcn_mfma_f32_16x16x32_bf16(a, b, acc, 0, 0, 0);
    }

    float bl = b_lin[col];
    float v[4];
#pragma unroll
    for (int r = 0; r < 4; ++r) {
        v[r] = fmaxf(acc[r] + bl, 0.f);
        float p = v[r] * v[r];
        p += __shfl_xor(p, 1);
        p += __shfl_xor(p, 2);
        p += __shfl_xor(p, 4);
        p += __shfl_xor(p, 8);
        if (li == 0) pn[w * 16 + kq * 4 + r] = p;
    }
    __syncthreads();
    if (tid < 16) {
        float s = 0.f;
#pragma unroll
        for (int ww = 0; ww < 8; ++ww) s += pn[ww * 16 + tid];
        pnt[tid] = s;
    }
    __syncthreads();
#pragma unroll
    for (int r = 0; r < 4; ++r) {
        int row = kq * 4 + r;
        float sc = 1.0f / fmaxf(sqrtf(pnt[row]), EPS);
        out[(size_t)(row0 + row) * 128 + col] = v[r] * sc;
    }
}

// ---------------- launch ----------------
extern "C" void kernel_launch(void* const* d_in, const int* in_sizes, int n_in,
                              void* d_out, int out_size, void* d_ws, size_t ws_size,
                              hipStream_t stream) {
    const int*   nbd      = (const int*)d_in[0];
    const int*   node_idx = (const int*)d_in[1];
    const float* feats    = (const float*)d_in[2];
    const float* W_agg    = (const float*)d_in[3];
    const float* b_agg    = (const float*)d_in[4];
    const float* W_lin    = (const float*)d_in[5];
    const float* b_lin    = (const float*)d_in[6];
    float* out = (float*)d_out;

    char* base = (char*)d_ws;
    size_t off = 0;
    int* inv  = (int*)(base + off); off += 50048 * 4;
    u16* Wab  = (u16*)(base + off); off += 16384 * 2;
    u16* Wlb  = (u16*)(base + off); off += 32768 * 2;
    u16* M0b  = (u16*)(base + off); off += (size_t)BATCH * 128 * 2;
    float* S  = (float*)(base + off); off += (size_t)BATCH * 128 * 4;
    u16* H1g  = (u16*)(base + off); off += (size_t)N_NODES * 128 * 2;
    u16* M1   = (u16*)(base + off); off += (size_t)N_NODES * 128 * 2;
    u16* AB2  = (u16*)(base + off); off += (size_t)BATCH * 256 * 2;

    const int GB = (N_NODES + 31) / 32;  // 1563

    prep_k<<<(50048 + 16384 + 32768 + 255) / 256, 256, 0, stream>>>(W_agg, W_lin, inv, Wab, Wlb);

    head_k<<<BATCH / 16, 512, 0, stream>>>(feats, Wab, Wlb, b_agg, node_idx, inv, M0b, S);

    hop1_k<<<GB, 256, 0, stream>>>(nbd, inv, M0b, b_agg, b_lin, S, Wlb, Wab, H1g, M1);

    tailg_k<<<BATCH, 128, 0, stream>>>(nbd, node_idx, H1g, M1, AB2);

    tail_k<<<BATCH / 16, 512, 0, stream>>>(AB2, Wlb, b_lin, out);
}